// Round 14
// baseline (28.069 us; speedup 1.0000x reference)
//
#include <hip/hip_runtime.h>
#include <hip/hip_fp16.h>

#define HI 256
#define WI 256
#define HO 1024
#define WO 1024
#define SC (255.0f / 1023.0f)
#define F5L2E 7.2134752f   // 5*log2(e)
#define EXPM5 0.0067379470f
#define GW0 0.27406862f
#define GW1 0.45186276f
#define C02 0.13862944f    // 0.2*ln(2)
#define EST 22             // E1 / hres row stride (uints)
#define SLS 19             // slice row stride (floats)

__device__ __forceinline__ int basef(int g) {
    int yc = min(max(g, 0), HO - 1);
    return (int)floorf((float)yc * SC) - 2;
}

// Combined conv(gauss3, keys-cubic4) 6-tap. OOB coord -> all-zero weights (so
// the E1 fma chain yields exp2(-F5L2E) = exp(-5) = the zero-pad value).
__device__ __forceinline__ void tap6(int g, int* base_out, float w[6]) {
    int yc = min(max(g, 0), HO - 1);
    int base = basef(g);
#pragma unroll
    for (int s = 0; s < 6; ++s) w[s] = 0.0f;
    if (g >= 0 && g < HO) {
#pragma unroll
        for (int d = -1; d <= 1; ++d) {
            int yd = yc + d;
            if (yd < 0 || yd >= HO) continue;
            float src = (float)yd * SC;
            float fi0 = floorf(src);
            float tt = src - fi0;
            const float a = -0.75f;
            float t1 = tt + 1.0f;
            float c0 = ((a * t1 - 5.0f * a) * t1 + 8.0f * a) * t1 - 4.0f * a;
            float c1 = ((a + 2.0f) * tt - (a + 3.0f)) * tt * tt + 1.0f;
            float u = 1.0f - tt;
            float c2 = ((a + 2.0f) * u - (a + 3.0f)) * u * u + 1.0f;
            float u2 = 2.0f - tt;
            float c3 = ((a * u2 - 5.0f * a) * u2 + 8.0f * a) * u2 - 4.0f * a;
            int s0 = ((int)fi0 - 1) - base;   // in [0,2]
            float gg = (d == 0) ? GW1 : GW0;
            w[s0 + 0] += gg * c0;
            w[s0 + 1] += gg * c1;
            w[s0 + 2] += gg * c2;
            w[s0 + 3] += gg * c3;
        }
    }
    *base_out = base;
}

// pad 6 weights into an 8-slot window at shift d in {0,1,2}, static indexing
__device__ __forceinline__ void pad8(const float w[6], int d, float scl, float w8[8]) {
#pragma unroll
    for (int j = 0; j < 8; ++j) {
        float v0 = (j < 6) ? w[j] : 0.0f;
        float v1 = (j >= 1 && j < 7) ? w[j - 1] : 0.0f;
        float v2 = (j >= 2) ? w[j - 2] : 0.0f;
        w8[j] = ((d == 0) ? v0 : (d == 1) ? v1 : v2) * scl;
    }
}

__device__ __forceinline__ uint4 packw8(const float w8[8]) {
    uint4 r;
    r.x = __builtin_bit_cast(unsigned int, __floats2half2_rn(w8[0], w8[1]));
    r.y = __builtin_bit_cast(unsigned int, __floats2half2_rn(w8[2], w8[3]));
    r.z = __builtin_bit_cast(unsigned int, __floats2half2_rn(w8[4], w8[5]));
    r.w = __builtin_bit_cast(unsigned int, __floats2half2_rn(w8[6], w8[7]));
    return r;
}

__device__ __forceinline__ void unpackw8(uint4 p, float w[8]) {
    __half2 a = __builtin_bit_cast(__half2, p.x);
    __half2 b = __builtin_bit_cast(__half2, p.y);
    __half2 c = __builtin_bit_cast(__half2, p.z);
    __half2 d = __builtin_bit_cast(__half2, p.w);
    w[0] = __low2float(a);  w[1] = __high2float(a);
    w[2] = __low2float(b);  w[3] = __high2float(b);
    w[4] = __low2float(c);  w[5] = __high2float(c);
    w[6] = __low2float(d);  w[7] = __high2float(d);
}

__device__ __forceinline__ void unpack4(uint2 u, float f[4]) {
    __half2 a = __builtin_bit_cast(__half2, u.x);
    __half2 b = __builtin_bit_cast(__half2, u.y);
    f[0] = __low2float(a); f[1] = __high2float(a);
    f[2] = __low2float(b); f[3] = __high2float(b);
}

// One wave = one 32x32 output tile. NO __syncthreads anywhere: every
// producer->consumer hop is within the wave (LDS ordering via lgkmcnt).
__global__ __launch_bounds__(256, 7) void k_fused(const float* __restrict__ in,
                                                  float* __restrict__ out) {
    __shared__ __align__(16) unsigned int Eu[4][36 * EST];   // E1 fp16, 3168 B/wave (slice aliases)
    __shared__ __align__(16) unsigned int Hu[4][16 * EST];   // hres fp16, 1408 B/wave
    __shared__ uint4 xWu[4][40];                             // 640 B/wave
    __shared__ uint4 vWu[4][36];                             // 576 B/wave  -> 23168 B/block

    const int tid = threadIdx.x;
    const int w = tid >> 6, lane = tid & 63;
    unsigned int* E1 = Eu[w];
    unsigned int* Hq = Hu[w];
    uint4* xW = xWu[w];
    uint4* vW = vWu[w];
    float* SL = (float*)E1;     // 16 x 19 floats, dead before stage B writes E1

    const int tx = (blockIdx.x << 2) + w, ty = blockIdx.y, b = blockIdx.z;
    const int gx0 = tx << 5, gy0 = ty << 5;
    const int rlo = basef(gy0 - 2);
    const int clo = basef(gx0 - 3);

    // ---- Phase 0a: weight tables ----
    if (lane < 36) {            // vertical, fy = lane+1, groups of 6
        int base; float w6[6];
        tap6(gy0 + (lane + 1) - 3, &base, w6);
        int bs = basef(gy0 + 6 * (lane / 6) - 2);
        float w8[8];
        pad8(w6, base - bs, F5L2E, w8);
        vW[lane] = packw8(w8);
    }
    if (lane < 40) {            // horizontal, fx = lane, groups of 4
        int base; float w6[6];
        tap6(gx0 + lane - 3, &base, w6);
        int bs = basef(gx0 + 4 * (lane >> 2) - 3);
        float w8[8];
        pad8(w6, base - bs, 1.0f, w8);
        xW[lane] = packw8(w8);
    }
    // ---- Phase 0b: sigmoid'd clamped input slice 16x18 ----
    {
        const float* pin = in + b * (HI * WI);
        for (int idx = lane; idx < 16 * 18; idx += 64) {
            int r = idx / 18;
            int cgi = idx - r * 18;
            int row = min(max(rlo + r, 0), HI - 1);
            int col = min(max(clo + cgi, 0), HI - 1);
            float x = pin[row * WI + col];
            SL[r * SLS + cgi] = 1.0f / (1.0f + __expf(-x));
        }
    }

    const int cg = lane / 10;         // row/col group [0,6); lanes 60..63 idle in A/B
    const int cc = lane - cg * 10;    // vec4-col [0,10)

    // ---- Stage A: horizontal 6-tap (8-window) -> hres fp16, rows 0..15 ----
    if (cg < 6) {
        int cbg = basef(gx0 + 4 * cc - 3) - clo;    // slice col window base
        float xw0[8], xw1[8], xw2[8], xw3[8];
        unpackw8(xW[4 * cc + 0], xw0);
        unpackw8(xW[4 * cc + 1], xw1);
        unpackw8(xW[4 * cc + 2], xw2);
        unpackw8(xW[4 * cc + 3], xw3);
        for (int r = cg; r < 16; r += 6) {
            const float* srow = SL + r * SLS + cbg;
            float wnd[8];
#pragma unroll
            for (int j = 0; j < 8; ++j) wnd[j] = srow[j];
            float s0 = wnd[0] * xw0[0], s1 = wnd[0] * xw1[0];
            float s2 = wnd[0] * xw2[0], s3 = wnd[0] * xw3[0];
#pragma unroll
            for (int j = 1; j < 8; ++j) {
                s0 = fmaf(wnd[j], xw0[j], s0);
                s1 = fmaf(wnd[j], xw1[j], s1);
                s2 = fmaf(wnd[j], xw2[j], s2);
                s3 = fmaf(wnd[j], xw3[j], s3);
            }
            unsigned int p0 = __builtin_bit_cast(unsigned int, __floats2half2_rn(s0, s1));
            unsigned int p1 = __builtin_bit_cast(unsigned int, __floats2half2_rn(s2, s3));
            *reinterpret_cast<uint2*>(&Hq[r * EST + 2 * cc]) = make_uint2(p0, p1);
        }
    }

    // ---- Stage B: vertical 6-tap (8-row reg window) + E1 = exp2 -> E1 fp16, fy 1..36 ----
    if (cg < 6) {
        int rb = basef(gy0 + 6 * cg - 2) - rlo;
        float hv0[4], hv1[4], hv2[4], hv3[4], hv4[4], hv5[4], hv6[4], hv7[4];
        unpack4(*reinterpret_cast<const uint2*>(&Hq[(rb + 0) * EST + 2 * cc]), hv0);
        unpack4(*reinterpret_cast<const uint2*>(&Hq[(rb + 1) * EST + 2 * cc]), hv1);
        unpack4(*reinterpret_cast<const uint2*>(&Hq[(rb + 2) * EST + 2 * cc]), hv2);
        unpack4(*reinterpret_cast<const uint2*>(&Hq[(rb + 3) * EST + 2 * cc]), hv3);
        unpack4(*reinterpret_cast<const uint2*>(&Hq[(rb + 4) * EST + 2 * cc]), hv4);
        unpack4(*reinterpret_cast<const uint2*>(&Hq[(rb + 5) * EST + 2 * cc]), hv5);
        unpack4(*reinterpret_cast<const uint2*>(&Hq[(rb + 6) * EST + 2 * cc]), hv6);
        unpack4(*reinterpret_cast<const uint2*>(&Hq[(rb + 7) * EST + 2 * cc]), hv7);
#pragma unroll
        for (int i = 0; i < 6; ++i) {
            int fy = 1 + 6 * cg + i;
            float wv[8];
            unpackw8(vW[fy - 1], wv);
            float ax = -F5L2E, ay = -F5L2E, az = -F5L2E, aw = -F5L2E;
#define ACC(H, J) ax = fmaf(wv[J], H[0], ax); ay = fmaf(wv[J], H[1], ay); \
                  az = fmaf(wv[J], H[2], az); aw = fmaf(wv[J], H[3], aw);
            ACC(hv0, 0) ACC(hv1, 1) ACC(hv2, 2) ACC(hv3, 3)
            ACC(hv4, 4) ACC(hv5, 5) ACC(hv6, 6) ACC(hv7, 7)
#undef ACC
            unsigned int p0 = __builtin_bit_cast(unsigned int, __floats2half2_rn(exp2f(ax), exp2f(ay)));
            unsigned int p1 = __builtin_bit_cast(unsigned int, __floats2half2_rn(exp2f(az), exp2f(aw)));
            *reinterpret_cast<uint2*>(&E1[(fy - 1) * EST + 2 * cc]) = make_uint2(p0, p1);
        }
    }

    // ---- Stage CD: rolling E2 (min) -> out (log), 4 rows/lane ----
    {
        const int dx = lane & 7;          // vec4 out col
        const int sq = lane >> 3;         // 4-row strip [0,8)
        const int lr0 = 4 * sq;
        const bool rT = (ty == 0)  && (sq == 0);
        const bool rB = (ty == 31) && (sq == 7);
        const bool cL = (tx == 0)  && (dx == 0);
        const bool cR = (tx == 31) && (dx == 7);

        // HSUM: E1 lds row lr, halfs 4dx+1 .. 4dx+8 -> 6 horizontal 3-sums
        auto HSUM = [&](int lr, float hs[6]) {
            uint2 ua = *reinterpret_cast<const uint2*>(&E1[lr * EST + 2 * dx]);
            uint2 ub = *reinterpret_cast<const uint2*>(&E1[lr * EST + 2 * dx + 2]);
            unsigned int uc = E1[lr * EST + 2 * dx + 4];
            float fa[4], fb[4];
            unpack4(ua, fa); unpack4(ub, fb);
            __half2 c2 = __builtin_bit_cast(__half2, uc);
            float f8 = __low2float(c2);
            // window halfs: fa[1..3], fb[0..3], f8  (centered 4dx+2+j)
            hs[0] = fa[1] + fa[2] + fa[3];
            hs[1] = fa[2] + fa[3] + fb[0];
            hs[2] = fa[3] + fb[0] + fb[1];
            hs[3] = fb[0] + fb[1] + fb[2];
            hs[4] = fb[1] + fb[2] + fb[3];
            hs[5] = fb[2] + fb[3] + f8;
        };
        auto E2F = [&](const float* a, const float* bq, const float* c, bool rowOv) -> float4 {
            float e[6];
#pragma unroll
            for (int j = 0; j < 6; ++j) e[j] = fminf(a[j] + bq[j] + c[j], 1.0f);
            if (rowOv) {
#pragma unroll
                for (int j = 0; j < 6; ++j) e[j] = EXPM5;
            }
            if (cL) e[0] = EXPM5;
            if (cR) e[5] = EXPM5;
            return make_float4(e[0] + e[1] + e[2], e[1] + e[2] + e[3],
                               e[2] + e[3] + e[4], e[3] + e[4] + e[5]);
        };
        auto OUTF = [&](float4 a, float4 bq, float4 c) -> float4 {
            float4 o;
            o.x = fmaxf(fminf(fmaf(C02, __log2f(a.x + bq.x + c.x), 1.0f), 1.0f), 0.0f);
            o.y = fmaxf(fminf(fmaf(C02, __log2f(a.y + bq.y + c.y), 1.0f), 1.0f), 0.0f);
            o.z = fmaxf(fminf(fmaf(C02, __log2f(a.z + bq.z + c.z), 1.0f), 1.0f), 0.0f);
            o.w = fmaxf(fminf(fmaf(C02, __log2f(a.w + bq.w + c.w), 1.0f), 1.0f), 0.0f);
            return o;
        };

        float hA[6], hB[6], hC[6], hD[6];
        size_t obase = ((size_t)(b * HO + gy0 + 4 * sq) * WO) + gx0 + (dx << 2);

        HSUM(lr0 + 0, hA); HSUM(lr0 + 1, hB); HSUM(lr0 + 2, hC);
        float4 eA = E2F(hA, hB, hC, rT);
        HSUM(lr0 + 3, hD); float4 eB = E2F(hB, hC, hD, false);
        HSUM(lr0 + 4, hA); float4 eC = E2F(hC, hD, hA, false);
        *reinterpret_cast<float4*>(out + obase) = OUTF(eA, eB, eC); obase += WO;
        HSUM(lr0 + 5, hB); float4 eD = E2F(hD, hA, hB, false);
        *reinterpret_cast<float4*>(out + obase) = OUTF(eB, eC, eD); obase += WO;
        HSUM(lr0 + 6, hC); float4 eE = E2F(hA, hB, hC, false);
        *reinterpret_cast<float4*>(out + obase) = OUTF(eC, eD, eE); obase += WO;
        HSUM(lr0 + 7, hD); float4 eF = E2F(hB, hC, hD, rB);
        *reinterpret_cast<float4*>(out + obase) = OUTF(eD, eE, eF);
    }
}

extern "C" void kernel_launch(void* const* d_in, const int* in_sizes, int n_in,
                              void* d_out, int out_size, void* d_ws, size_t ws_size,
                              hipStream_t stream) {
    const float* in = (const float*)d_in[0];
    float* out = (float*)d_out;
    dim3 g(8, 32, 8);   // 4 tiles (waves) per block in x; 32x32x8 tiles total
    k_fused<<<g, dim3(256), 0, stream>>>(in, out);
}

// Round 15
// 24.690 us; speedup vs baseline: 1.1369x; 1.1369x over previous
//
#include <hip/hip_runtime.h>
#include <hip/hip_fp16.h>

#define B_ 8
#define HI 256
#define WI 256
#define HO 1024
#define WO 1024

#define TLE 64            // output tile 64x64, grid 16x16x8
#define NRS 24            // staged low-res rows/cols
#define SSTR 25           // slice stride (floats)
#define HS 18             // hres row stride (vec4)
#define EW 38             // E1 half-row stride in uints (152 B, 72 halfs + pad)
#define SC (255.0f / 1023.0f)
#define F5L2E 7.2134752f  // 5*log2(e)
#define EXPM5 0.0067379470f
#define GW0 0.27406862f
#define GW1 0.45186276f
#define C02 0.13862944f   // 0.2*ln(2)

__device__ __forceinline__ int basef(int g) {
    int yc = min(max(g, 0), HO - 1);
    return (int)floorf((float)yc * SC) - 2;
}

// Combined conv(gauss3, keys-cubic4) 6-tap. OOB coord -> all-zero weights (so
// the E1 fma chain yields exp2(-F5L2E) = exp(-5) = the zero-pad value).
__device__ __forceinline__ void tap6(int g, int* base_out, float w[6]) {
    int yc = min(max(g, 0), HO - 1);
    int base = basef(g);
#pragma unroll
    for (int s = 0; s < 6; ++s) w[s] = 0.0f;
    if (g >= 0 && g < HO) {
#pragma unroll
        for (int d = -1; d <= 1; ++d) {
            int yd = yc + d;
            if (yd < 0 || yd >= HO) continue;
            float src = (float)yd * SC;
            float fi0 = floorf(src);
            float tt = src - fi0;
            const float a = -0.75f;
            float t1 = tt + 1.0f;
            float c0 = ((a * t1 - 5.0f * a) * t1 + 8.0f * a) * t1 - 4.0f * a;
            float c1 = ((a + 2.0f) * tt - (a + 3.0f)) * tt * tt + 1.0f;
            float u = 1.0f - tt;
            float c2 = ((a + 2.0f) * u - (a + 3.0f)) * u * u + 1.0f;
            float u2 = 2.0f - tt;
            float c3 = ((a * u2 - 5.0f * a) * u2 + 8.0f * a) * u2 - 4.0f * a;
            int s0 = ((int)fi0 - 1) - base;   // in [0,2]
            float gg = (d == 0) ? GW1 : GW0;
            w[s0 + 0] += gg * c0;
            w[s0 + 1] += gg * c1;
            w[s0 + 2] += gg * c2;
            w[s0 + 3] += gg * c3;
        }
    }
    *base_out = base;
}

// pad 6 weights into 8-slot window at shift d (0/1) without dynamic indexing
__device__ __forceinline__ void pad8(const float w[6], int d, float scl, float w8[8]) {
#pragma unroll
    for (int j = 0; j < 8; ++j) {
        float a = (j < 6) ? w[j] : 0.0f;
        float bq = (j >= 1 && j < 7) ? w[j - 1] : 0.0f;
        w8[j] = ((d == 0) ? a : bq) * scl;
    }
}

__global__ __launch_bounds__(256, 7) void k_fused(const float* __restrict__ in,
                                                  float* __restrict__ out) {
    __shared__ __align__(16) unsigned int Eu[68 * EW];   // E1 half, 10336 B (slice aliases)
    __shared__ float4 Hs[NRS * HS];                      // 6912 B
    __shared__ float4 xAw[72], xBw[72];                  // 2304 B
    __shared__ float4 vAw[70], vBw[70];                  // 2240 B
    __shared__ int vgb[14], xgb[18];                     // 128 B  -> 21.9 KB total
    float* SL = (float*)Eu;

    const int tid = threadIdx.x;
    const int bx = blockIdx.x, by = blockIdx.y, b = blockIdx.z;
    const int gy0 = by * TLE, gx0 = bx * TLE;
    const int rlo = basef(gy0 - 3);
    const int clo = basef(gx0 - 4);

    // ---- Phase 0a (T14 split): ISSUE the slice global loads first ----
    const float* pin = in + b * (HI * WI);
    float g0, g1, g2 = 0.0f;
    {
        int i0 = tid, i1 = tid + 256;
        int r0 = i0 / NRS, c0 = i0 - r0 * NRS;
        int r1 = i1 / NRS, c1 = i1 - r1 * NRS;
        g0 = pin[min(max(rlo + r0, 0), HI - 1) * WI + min(max(clo + c0, 0), HI - 1)];
        g1 = pin[min(max(rlo + r1, 0), HI - 1) * WI + min(max(clo + c1, 0), HI - 1)];
        if (tid < 64) {
            int i2 = tid + 512;
            int r2 = i2 / NRS, c2 = i2 - r2 * NRS;
            g2 = pin[min(max(rlo + r2, 0), HI - 1) * WI + min(max(clo + c2, 0), HI - 1)];
        }
    }

    // ---- Phase 0b: tables (independent VALU work covers the load latency) ----
    if (tid < 70) {                       // vertical weights, fy = tid+1
        int fy = tid + 1;
        int base; float w[6];
        tap6(gy0 + fy - 3, &base, w);
        int q = tid / 5;
        int bs = basef(gy0 + (1 + 5 * q) - 3);
        float w8[8];
        pad8(w, base - bs, F5L2E, w8);
        vAw[tid] = make_float4(w8[0], w8[1], w8[2], w8[3]);
        vBw[tid] = make_float4(w8[4], w8[5], w8[6], w8[7]);
    } else if (tid < 84) {
        vgb[tid - 70] = basef(gy0 + (1 + 5 * (tid - 70)) - 3);
    } else if (tid < 102) {
        xgb[tid - 84] = basef(gx0 + 4 * (tid - 84) - 4);
    } else if (tid >= 128 && tid < 200) { // horizontal weights, xe = tid-128
        int xe = tid - 128;
        int base; float w[6];
        tap6(gx0 + xe - 4, &base, w);
        int bs = basef(gx0 + (xe & ~3) - 4);
        float w8[8];
        pad8(w, base - bs, 1.0f, w8);
        xAw[xe] = make_float4(w8[0], w8[1], w8[2], w8[3]);
        xBw[xe] = make_float4(w8[4], w8[5], w8[6], w8[7]);
    }

    // ---- Phase 0c: sigmoid + LDS write of the slice ----
    {
        int i0 = tid, i1 = tid + 256;
        int r0 = i0 / NRS, c0 = i0 - r0 * NRS;
        int r1 = i1 / NRS, c1 = i1 - r1 * NRS;
        SL[r0 * SSTR + c0] = 1.0f / (1.0f + __expf(-g0));
        SL[r1 * SSTR + c1] = 1.0f / (1.0f + __expf(-g1));
        if (tid < 64) {
            int i2 = tid + 512;
            int r2 = i2 / NRS, c2 = i2 - r2 * NRS;
            SL[r2 * SSTR + c2] = 1.0f / (1.0f + __expf(-g2));
        }
    }
    __syncthreads();

    const int ty = tid / HS;          // [0,14) for tid < 252
    const int tx = tid - ty * HS;

    // ---- Stage A: horizontal 8-window 6-tap -> Hs[24][18] ----
    if (tid < 252) {
        int cbg = xgb[tx] - clo;
        int wc[8];
#pragma unroll
        for (int j = 0; j < 8; ++j) wc[j] = min(cbg + j, NRS - 1);
        float xw0[8], xw1[8], xw2[8], xw3[8];
        {
            int xe0 = tx << 2;
            float4 a0 = xAw[xe0 + 0], b0 = xBw[xe0 + 0];
            float4 a1 = xAw[xe0 + 1], b1 = xBw[xe0 + 1];
            float4 a2 = xAw[xe0 + 2], b2 = xBw[xe0 + 2];
            float4 a3 = xAw[xe0 + 3], b3 = xBw[xe0 + 3];
            xw0[0]=a0.x; xw0[1]=a0.y; xw0[2]=a0.z; xw0[3]=a0.w; xw0[4]=b0.x; xw0[5]=b0.y; xw0[6]=b0.z; xw0[7]=b0.w;
            xw1[0]=a1.x; xw1[1]=a1.y; xw1[2]=a1.z; xw1[3]=a1.w; xw1[4]=b1.x; xw1[5]=b1.y; xw1[6]=b1.z; xw1[7]=b1.w;
            xw2[0]=a2.x; xw2[1]=a2.y; xw2[2]=a2.z; xw2[3]=a2.w; xw2[4]=b2.x; xw2[5]=b2.y; xw2[6]=b2.z; xw2[7]=b2.w;
            xw3[0]=a3.x; xw3[1]=a3.y; xw3[2]=a3.z; xw3[3]=a3.w; xw3[4]=b3.x; xw3[5]=b3.y; xw3[6]=b3.z; xw3[7]=b3.w;
        }
        for (int r = ty; r < NRS; r += 14) {
            const float* srow = SL + r * SSTR;
            float wnd[8];
#pragma unroll
            for (int j = 0; j < 8; ++j) wnd[j] = srow[wc[j]];
            float s0 = wnd[0]*xw0[0], s1 = wnd[0]*xw1[0], s2 = wnd[0]*xw2[0], s3 = wnd[0]*xw3[0];
#pragma unroll
            for (int j = 1; j < 8; ++j) {
                s0 = fmaf(wnd[j], xw0[j], s0);
                s1 = fmaf(wnd[j], xw1[j], s1);
                s2 = fmaf(wnd[j], xw2[j], s2);
                s3 = fmaf(wnd[j], xw3[j], s3);
            }
            Hs[r * HS + tx] = make_float4(s0, s1, s2, s3);
        }
    }
    __syncthreads();

    // ---- Stage B: vertical 8-row register window -> E1 (half2) rows fy 1..68 ----
    if (tid < 252) {
        const int q = ty;
        const int rbase = vgb[q] - rlo;
        float4 h[8];
#pragma unroll
        for (int i = 0; i < 8; ++i) h[i] = Hs[min(rbase + i, NRS - 1) * HS + tx];
#pragma unroll
        for (int i = 0; i < 5; ++i) {
            int fy = 1 + 5 * q + i;
            if (fy <= 68) {
                float4 wa = vAw[fy - 1], wb = vBw[fy - 1];
                const float wv[8] = {wa.x, wa.y, wa.z, wa.w, wb.x, wb.y, wb.z, wb.w};
                float ax = -F5L2E, ay = -F5L2E, az = -F5L2E, aw = -F5L2E;
#pragma unroll
                for (int j = 0; j < 8; ++j) {
                    ax = fmaf(wv[j], h[j].x, ax);
                    ay = fmaf(wv[j], h[j].y, ay);
                    az = fmaf(wv[j], h[j].z, az);
                    aw = fmaf(wv[j], h[j].w, aw);
                }
                unsigned int p0 = __builtin_bit_cast(unsigned int, __floats2half2_rn(exp2f(ax), exp2f(ay)));
                unsigned int p1 = __builtin_bit_cast(unsigned int, __floats2half2_rn(exp2f(az), exp2f(aw)));
                *reinterpret_cast<uint2*>(&Eu[(fy - 1) * EW + 2 * tx]) = make_uint2(p0, p1);
            }
        }
    }
    __syncthreads();

    // ---- Stage CD: rolling E2 (min) -> out (log), fp16 E1 reads, 4 rows/thread ----
    {
        const int dx = tid & 15;
        const int sq = tid >> 4;
        const int lr0 = 4 * sq;
        const bool rT = (by == 0)  && (sq == 0);
        const bool rB = (by == 15) && (sq == 15);
        const bool cL = (bx == 0)  && (dx == 0);
        const bool cR = (bx == 15) && (dx == 15);

        // HSUM: E1 half row lr, frame half cols [4dx+2 .. 4dx+9] -> 6 sums
        auto HSUM = [&](int lr, float hs[6]) {
            unsigned int ua = Eu[lr * EW + 2 * dx + 1];                                 // halfs 4dx+2,3
            uint2 ub = *reinterpret_cast<const uint2*>(&Eu[lr * EW + 2 * dx + 2]);      // halfs 4dx+4..7
            unsigned int uc = Eu[lr * EW + 2 * dx + 4];                                 // halfs 4dx+8,9
            __half2 A2 = __builtin_bit_cast(__half2, ua);
            __half2 B2 = __builtin_bit_cast(__half2, ub.x);
            __half2 C2 = __builtin_bit_cast(__half2, ub.y);
            __half2 D2 = __builtin_bit_cast(__half2, uc);
            float e0 = __low2float(A2), e1 = __high2float(A2);
            float e2 = __low2float(B2), e3 = __high2float(B2);
            float e4 = __low2float(C2), e5 = __high2float(C2);
            float e6 = __low2float(D2), e7 = __high2float(D2);
            hs[0] = e0 + e1 + e2;
            hs[1] = e1 + e2 + e3;
            hs[2] = e2 + e3 + e4;
            hs[3] = e3 + e4 + e5;
            hs[4] = e4 + e5 + e6;
            hs[5] = e5 + e6 + e7;
        };
        auto E2F = [&](const float* a, const float* bq, const float* c, bool rowOv) -> float4 {
            float e[6];
#pragma unroll
            for (int j = 0; j < 6; ++j) e[j] = fminf(a[j] + bq[j] + c[j], 1.0f);
            if (rowOv) {
#pragma unroll
                for (int j = 0; j < 6; ++j) e[j] = EXPM5;
            }
            if (cL) e[0] = EXPM5;
            if (cR) e[5] = EXPM5;
            return make_float4(e[0] + e[1] + e[2], e[1] + e[2] + e[3],
                               e[2] + e[3] + e[4], e[3] + e[4] + e[5]);
        };
        auto OUTF = [&](float4 a, float4 bq, float4 c) -> float4 {
            float4 o;
            o.x = fmaxf(fminf(fmaf(C02, __log2f(a.x + bq.x + c.x), 1.0f), 1.0f), 0.0f);
            o.y = fmaxf(fminf(fmaf(C02, __log2f(a.y + bq.y + c.y), 1.0f), 1.0f), 0.0f);
            o.z = fmaxf(fminf(fmaf(C02, __log2f(a.z + bq.z + c.z), 1.0f), 1.0f), 0.0f);
            o.w = fmaxf(fminf(fmaf(C02, __log2f(a.w + bq.w + c.w), 1.0f), 1.0f), 0.0f);
            return o;
        };

        float hA[6], hB[6], hC[6], hD[6];
        size_t obase = ((size_t)(b * HO + by * TLE + 4 * sq) * WO) + bx * TLE + (dx << 2);

        HSUM(lr0 + 0, hA); HSUM(lr0 + 1, hB); HSUM(lr0 + 2, hC);
        float4 eA = E2F(hA, hB, hC, rT);
        HSUM(lr0 + 3, hD); float4 eB = E2F(hB, hC, hD, false);
        HSUM(lr0 + 4, hA); float4 eC = E2F(hC, hD, hA, false);
        *reinterpret_cast<float4*>(out + obase) = OUTF(eA, eB, eC); obase += WO;
        HSUM(lr0 + 5, hB); float4 eD = E2F(hD, hA, hB, false);
        *reinterpret_cast<float4*>(out + obase) = OUTF(eB, eC, eD); obase += WO;
        HSUM(lr0 + 6, hC); float4 eE = E2F(hA, hB, hC, false);
        *reinterpret_cast<float4*>(out + obase) = OUTF(eC, eD, eE); obase += WO;
        HSUM(lr0 + 7, hD); float4 eF = E2F(hB, hC, hD, rB);
        *reinterpret_cast<float4*>(out + obase) = OUTF(eD, eE, eF);
    }
}

extern "C" void kernel_launch(void* const* d_in, const int* in_sizes, int n_in,
                              void* d_out, int out_size, void* d_ws, size_t ws_size,
                              hipStream_t stream) {
    const float* in = (const float*)d_in[0];
    float* out = (float*)d_out;
    dim3 g(WO / TLE, HO / TLE, B_);   // (16,16,8)
    k_fused<<<g, dim3(256), 0, stream>>>(in, out);
}

// Round 18
// 23.350 us; speedup vs baseline: 1.2021x; 1.0574x over previous
//
#include <hip/hip_runtime.h>
#include <hip/hip_fp16.h>

#define B_ 8
#define HI 256
#define WI 256
#define HO 1024
#define WO 1024

#define TLE 64            // output tile 64x64, grid 16x16x8
#define NRS 24            // staged low-res rows/cols
#define SSTR 25           // slice stride (floats)
#define HS 18             // hres row stride (vec4)
#define EW 38             // E1 half-row stride in uints (152 B, 72 halfs + pad)
#define SC (255.0f / 1023.0f)
#define F5L2E 7.2134752f  // 5*log2(e)
#define EXPM5 0.0067379470f
#define GW0 0.27406862f
#define GW1 0.45186276f
#define C02 0.13862944f   // 0.2*ln(2)

__device__ __forceinline__ int basef(int g) {
    int yc = min(max(g, 0), HO - 1);
    return (int)floorf((float)yc * SC) - 2;
}

// Combined conv(gauss3, keys-cubic4) 6-tap. OOB coord -> all-zero weights (so
// the E1 fma chain yields exp2(-F5L2E) = exp(-5) = the zero-pad value).
__device__ __forceinline__ void tap6(int g, int* base_out, float w[6]) {
    int yc = min(max(g, 0), HO - 1);
    int base = basef(g);
#pragma unroll
    for (int s = 0; s < 6; ++s) w[s] = 0.0f;
    if (g >= 0 && g < HO) {
#pragma unroll
        for (int d = -1; d <= 1; ++d) {
            int yd = yc + d;
            if (yd < 0 || yd >= HO) continue;
            float src = (float)yd * SC;
            float fi0 = floorf(src);
            float tt = src - fi0;
            const float a = -0.75f;
            float t1 = tt + 1.0f;
            float c0 = ((a * t1 - 5.0f * a) * t1 + 8.0f * a) * t1 - 4.0f * a;
            float c1 = ((a + 2.0f) * tt - (a + 3.0f)) * tt * tt + 1.0f;
            float u = 1.0f - tt;
            float c2 = ((a + 2.0f) * u - (a + 3.0f)) * u * u + 1.0f;
            float u2 = 2.0f - tt;
            float c3 = ((a * u2 - 5.0f * a) * u2 + 8.0f * a) * u2 - 4.0f * a;
            int s0 = ((int)fi0 - 1) - base;   // in [0,2]
            float gg = (d == 0) ? GW1 : GW0;
            w[s0 + 0] += gg * c0;
            w[s0 + 1] += gg * c1;
            w[s0 + 2] += gg * c2;
            w[s0 + 3] += gg * c3;
        }
    }
    *base_out = base;
}

// pad 6 weights into 8-slot window at shift d (0/1) without dynamic indexing
__device__ __forceinline__ void pad8(const float w[6], int d, float scl, float w8[8]) {
#pragma unroll
    for (int j = 0; j < 8; ++j) {
        float a = (j < 6) ? w[j] : 0.0f;
        float bq = (j >= 1 && j < 7) ? w[j - 1] : 0.0f;
        w8[j] = ((d == 0) ? a : bq) * scl;
    }
}

// packed fp16 min — ROCm 7.2 headers lack __hmin2; emit v_pk_min_f16 directly
__device__ __forceinline__ __half2 hmin2(__half2 a, __half2 b) {
    unsigned int ua = __builtin_bit_cast(unsigned int, a);
    unsigned int ub = __builtin_bit_cast(unsigned int, b);
    unsigned int r;
    asm("v_pk_min_f16 %0, %1, %2" : "=v"(r) : "v"(ua), "v"(ub));
    return __builtin_bit_cast(__half2, r);
}

__global__ __launch_bounds__(256, 7) void k_fused(const float* __restrict__ in,
                                                  float* __restrict__ out) {
    __shared__ __align__(16) unsigned int Eu[68 * EW];   // E1 half, 10336 B (slice aliases)
    __shared__ float4 Hs[NRS * HS];                      // 6912 B
    __shared__ float4 xAw[72], xBw[72];                  // 2304 B
    __shared__ float4 vAw[70], vBw[70];                  // 2240 B
    __shared__ int vgb[14], xgb[18];                     // 128 B  -> 21.9 KB total
    float* SL = (float*)Eu;

    const int tid = threadIdx.x;
    const int bx = blockIdx.x, by = blockIdx.y, b = blockIdx.z;
    const int gy0 = by * TLE, gx0 = bx * TLE;
    const int rlo = basef(gy0 - 3);
    const int clo = basef(gx0 - 4);

    // ---- Phase 0a: issue slice global loads first (latency covered by 0b) ----
    const float* pin = in + b * (HI * WI);
    float g0, g1, g2 = 0.0f;
    {
        int i0 = tid, i1 = tid + 256;
        int r0 = i0 / NRS, c0 = i0 - r0 * NRS;
        int r1 = i1 / NRS, c1 = i1 - r1 * NRS;
        g0 = pin[min(max(rlo + r0, 0), HI - 1) * WI + min(max(clo + c0, 0), HI - 1)];
        g1 = pin[min(max(rlo + r1, 0), HI - 1) * WI + min(max(clo + c1, 0), HI - 1)];
        if (tid < 64) {
            int i2 = tid + 512;
            int r2 = i2 / NRS, c2 = i2 - r2 * NRS;
            g2 = pin[min(max(rlo + r2, 0), HI - 1) * WI + min(max(clo + c2, 0), HI - 1)];
        }
    }

    // ---- Phase 0b: tables ----
    if (tid < 70) {                       // vertical weights, fy = tid+1
        int fy = tid + 1;
        int base; float w[6];
        tap6(gy0 + fy - 3, &base, w);
        int q = tid / 5;
        int bs = basef(gy0 + (1 + 5 * q) - 3);
        float w8[8];
        pad8(w, base - bs, F5L2E, w8);
        vAw[tid] = make_float4(w8[0], w8[1], w8[2], w8[3]);
        vBw[tid] = make_float4(w8[4], w8[5], w8[6], w8[7]);
    } else if (tid < 84) {
        vgb[tid - 70] = basef(gy0 + (1 + 5 * (tid - 70)) - 3);
    } else if (tid < 102) {
        xgb[tid - 84] = basef(gx0 + 4 * (tid - 84) - 4);
    } else if (tid >= 128 && tid < 200) { // horizontal weights, xe = tid-128
        int xe = tid - 128;
        int base; float w[6];
        tap6(gx0 + xe - 4, &base, w);
        int bs = basef(gx0 + (xe & ~3) - 4);
        float w8[8];
        pad8(w, base - bs, 1.0f, w8);
        xAw[xe] = make_float4(w8[0], w8[1], w8[2], w8[3]);
        xBw[xe] = make_float4(w8[4], w8[5], w8[6], w8[7]);
    }

    // ---- Phase 0c: sigmoid + LDS write of the slice ----
    {
        int i0 = tid, i1 = tid + 256;
        int r0 = i0 / NRS, c0 = i0 - r0 * NRS;
        int r1 = i1 / NRS, c1 = i1 - r1 * NRS;
        SL[r0 * SSTR + c0] = 1.0f / (1.0f + __expf(-g0));
        SL[r1 * SSTR + c1] = 1.0f / (1.0f + __expf(-g1));
        if (tid < 64) {
            int i2 = tid + 512;
            int r2 = i2 / NRS, c2 = i2 - r2 * NRS;
            SL[r2 * SSTR + c2] = 1.0f / (1.0f + __expf(-g2));
        }
    }
    __syncthreads();

    const int ty = tid / HS;          // [0,14) for tid < 252
    const int tx = tid - ty * HS;

    // ---- Stage A: horizontal 8-window 6-tap -> Hs[24][18] ----
    if (tid < 252) {
        int cbg = xgb[tx] - clo;
        int wc[8];
#pragma unroll
        for (int j = 0; j < 8; ++j) wc[j] = min(cbg + j, NRS - 1);
        float xw0[8], xw1[8], xw2[8], xw3[8];
        {
            int xe0 = tx << 2;
            float4 a0 = xAw[xe0 + 0], b0 = xBw[xe0 + 0];
            float4 a1 = xAw[xe0 + 1], b1 = xBw[xe0 + 1];
            float4 a2 = xAw[xe0 + 2], b2 = xBw[xe0 + 2];
            float4 a3 = xAw[xe0 + 3], b3 = xBw[xe0 + 3];
            xw0[0]=a0.x; xw0[1]=a0.y; xw0[2]=a0.z; xw0[3]=a0.w; xw0[4]=b0.x; xw0[5]=b0.y; xw0[6]=b0.z; xw0[7]=b0.w;
            xw1[0]=a1.x; xw1[1]=a1.y; xw1[2]=a1.z; xw1[3]=a1.w; xw1[4]=b1.x; xw1[5]=b1.y; xw1[6]=b1.z; xw1[7]=b1.w;
            xw2[0]=a2.x; xw2[1]=a2.y; xw2[2]=a2.z; xw2[3]=a2.w; xw2[4]=b2.x; xw2[5]=b2.y; xw2[6]=b2.z; xw2[7]=b2.w;
            xw3[0]=a3.x; xw3[1]=a3.y; xw3[2]=a3.z; xw3[3]=a3.w; xw3[4]=b3.x; xw3[5]=b3.y; xw3[6]=b3.z; xw3[7]=b3.w;
        }
        for (int r = ty; r < NRS; r += 14) {
            const float* srow = SL + r * SSTR;
            float wnd[8];
#pragma unroll
            for (int j = 0; j < 8; ++j) wnd[j] = srow[wc[j]];
            float s0 = wnd[0]*xw0[0], s1 = wnd[0]*xw1[0], s2 = wnd[0]*xw2[0], s3 = wnd[0]*xw3[0];
#pragma unroll
            for (int j = 1; j < 8; ++j) {
                s0 = fmaf(wnd[j], xw0[j], s0);
                s1 = fmaf(wnd[j], xw1[j], s1);
                s2 = fmaf(wnd[j], xw2[j], s2);
                s3 = fmaf(wnd[j], xw3[j], s3);
            }
            Hs[r * HS + tx] = make_float4(s0, s1, s2, s3);
        }
    }
    __syncthreads();

    // ---- Stage B: vertical 8-row register window -> E1 (half2) rows fy 1..68 ----
    if (tid < 252) {
        const int q = ty;
        const int rbase = vgb[q] - rlo;
        float4 h[8];
#pragma unroll
        for (int i = 0; i < 8; ++i) h[i] = Hs[min(rbase + i, NRS - 1) * HS + tx];
#pragma unroll
        for (int i = 0; i < 5; ++i) {
            int fy = 1 + 5 * q + i;
            if (fy <= 68) {
                float4 wa = vAw[fy - 1], wb = vBw[fy - 1];
                const float wv[8] = {wa.x, wa.y, wa.z, wa.w, wb.x, wb.y, wb.z, wb.w};
                float ax = -F5L2E, ay = -F5L2E, az = -F5L2E, aw = -F5L2E;
#pragma unroll
                for (int j = 0; j < 8; ++j) {
                    ax = fmaf(wv[j], h[j].x, ax);
                    ay = fmaf(wv[j], h[j].y, ay);
                    az = fmaf(wv[j], h[j].z, az);
                    aw = fmaf(wv[j], h[j].w, aw);
                }
                unsigned int p0 = __builtin_bit_cast(unsigned int, __floats2half2_rn(exp2f(ax), exp2f(ay)));
                unsigned int p1 = __builtin_bit_cast(unsigned int, __floats2half2_rn(exp2f(az), exp2f(aw)));
                *reinterpret_cast<uint2*>(&Eu[(fy - 1) * EW + 2 * tx]) = make_uint2(p0, p1);
            }
        }
    }
    __syncthreads();

    // ---- Stage CD: PACKED fp16 rolling E2 (pk_min) -> out (log), 4 rows/thread ----
    {
        const int dx = tid & 15;
        const int sq = tid >> 4;
        const int lr0 = 4 * sq;
        const bool rT = (by == 0)  && (sq == 0);
        const bool rB = (by == 15) && (sq == 15);
        const bool cL = (bx == 0)  && (dx == 0);
        const bool cR = (bx == 15) && (dx == 15);

        const __half2 ONE2 = __floats2half2_rn(1.0f, 1.0f);
        const __half2 EX2  = __floats2half2_rn(EXPM5, EXPM5);
        const unsigned int exu = __builtin_bit_cast(unsigned int, EX2);

        auto H2  = [](unsigned int u) { return __builtin_bit_cast(__half2, u); };
        auto U32 = [](__half2 h) { return __builtin_bit_cast(unsigned int, h); };

        // packed horizontal 3-sums of E1 row lr, halfs 4dx+2..4dx+9 -> P[0..2]=(hs0..hs5)
        auto HSUM = [&](int lr, __half2 P[3]) {
            const int o = lr * EW + 2 * dx;
            unsigned int a = Eu[o + 1];
            uint2 bc = *reinterpret_cast<const uint2*>(&Eu[o + 2]);
            unsigned int d = Eu[o + 4];
            unsigned int ab  = (a >> 16) | (bc.x << 16);      // (h1,h2)
            unsigned int bcx = (bc.x >> 16) | (bc.y << 16);   // (h3,h4)
            unsigned int cd  = (bc.y >> 16) | (d << 16);      // (h5,h6)
            P[0] = __hadd2(__hadd2(H2(a), H2(ab)), H2(bc.x));     // (hs0,hs1)
            P[1] = __hadd2(__hadd2(H2(bc.x), H2(bcx)), H2(bc.y)); // (hs2,hs3)
            P[2] = __hadd2(__hadd2(H2(bc.y), H2(cd)), H2(d));     // (hs4,hs5)
        };
        // E2 row = min(3-row sum, 1) + boundary overrides, then horiz 3-sum -> Q[0..1]
        auto E2F = [&](const __half2* a, const __half2* bq, const __half2* c,
                       bool rowOv, __half2 Q[2]) {
            __half2 e0 = hmin2(__hadd2(__hadd2(a[0], bq[0]), c[0]), ONE2);
            __half2 e1 = hmin2(__hadd2(__hadd2(a[1], bq[1]), c[1]), ONE2);
            __half2 e2 = hmin2(__hadd2(__hadd2(a[2], bq[2]), c[2]), ONE2);
            if (rowOv) { e0 = EX2; e1 = EX2; e2 = EX2; }
            if (cL) e0 = H2((U32(e0) & 0xFFFF0000u) | (exu & 0x0000FFFFu));
            if (cR) e2 = H2((U32(e2) & 0x0000FFFFu) | (exu & 0xFFFF0000u));
            unsigned int u0 = U32(e0), u1 = U32(e1), u2 = U32(e2);
            unsigned int e01 = (u0 >> 16) | (u1 << 16);
            unsigned int e12 = (u1 >> 16) | (u2 << 16);
            Q[0] = __hadd2(__hadd2(e0, H2(e01)), e1);   // (E0+E1+E2, E1+E2+E3)
            Q[1] = __hadd2(__hadd2(e1, H2(e12)), e2);   // (E2+E3+E4, E3+E4+E5)
        };
        auto OUTF = [&](const __half2* qa, const __half2* qb, const __half2* qc) -> float4 {
            __half2 s0 = __hadd2(__hadd2(qa[0], qb[0]), qc[0]);
            __half2 s1 = __hadd2(__hadd2(qa[1], qb[1]), qc[1]);
            float f0 = __low2float(s0), f1 = __high2float(s0);
            float f2 = __low2float(s1), f3 = __high2float(s1);
            float4 o;
            o.x = fmaxf(fminf(fmaf(C02, __log2f(f0), 1.0f), 1.0f), 0.0f);
            o.y = fmaxf(fminf(fmaf(C02, __log2f(f1), 1.0f), 1.0f), 0.0f);
            o.z = fmaxf(fminf(fmaf(C02, __log2f(f2), 1.0f), 1.0f), 0.0f);
            o.w = fmaxf(fminf(fmaf(C02, __log2f(f3), 1.0f), 1.0f), 0.0f);
            return o;
        };

        __half2 hA[3], hB[3], hC[3], hD[3];
        __half2 eA[2], eB[2], eC[2], eD[2], eE[2], eF[2];
        size_t obase = ((size_t)(b * HO + by * TLE + 4 * sq) * WO) + bx * TLE + (dx << 2);

        HSUM(lr0 + 0, hA); HSUM(lr0 + 1, hB); HSUM(lr0 + 2, hC);
        E2F(hA, hB, hC, rT, eA);
        HSUM(lr0 + 3, hD); E2F(hB, hC, hD, false, eB);
        HSUM(lr0 + 4, hA); E2F(hC, hD, hA, false, eC);
        *reinterpret_cast<float4*>(out + obase) = OUTF(eA, eB, eC); obase += WO;
        HSUM(lr0 + 5, hB); E2F(hD, hA, hB, false, eD);
        *reinterpret_cast<float4*>(out + obase) = OUTF(eB, eC, eD); obase += WO;
        HSUM(lr0 + 6, hC); E2F(hA, hB, hC, false, eE);
        *reinterpret_cast<float4*>(out + obase) = OUTF(eC, eD, eE); obase += WO;
        HSUM(lr0 + 7, hD); E2F(hB, hC, hD, rB, eF);
        *reinterpret_cast<float4*>(out + obase) = OUTF(eD, eE, eF);
    }
}

extern "C" void kernel_launch(void* const* d_in, const int* in_sizes, int n_in,
                              void* d_out, int out_size, void* d_ws, size_t ws_size,
                              hipStream_t stream) {
    const float* in = (const float*)d_in[0];
    float* out = (float*)d_out;
    dim3 g(WO / TLE, HO / TLE, B_);   // (16,16,8)
    k_fused<<<g, dim3(256), 0, stream>>>(in, out);
}

// Round 22
// 23.269 us; speedup vs baseline: 1.2063x; 1.0035x over previous
//
#include <hip/hip_runtime.h>
#include <hip/hip_fp16.h>

#define B_ 8
#define HI 256
#define WI 256
#define HO 1024
#define WO 1024

#define TLE 64            // output tile 64x64, grid 16x16x8
#define NRS 24            // staged low-res rows/cols
#define SSTR 25           // slice stride (floats)
#define EW 38             // E1/hres half-row stride in uints (152 B)
#define SC (255.0f / 1023.0f)
#define F5L2E 7.2134752f  // 5*log2(e)
#define EXPM5 0.0067379470f
#define GW0 0.27406862f
#define GW1 0.45186276f
#define C02 0.13862944f   // 0.2*ln(2)

typedef _Float16 f16x2 __attribute__((ext_vector_type(2)));

__device__ __forceinline__ float dot2(unsigned int a, unsigned int b, float c) {
    return __builtin_amdgcn_fdot2(__builtin_bit_cast(f16x2, a),
                                  __builtin_bit_cast(f16x2, b), c, false);
}

__device__ __forceinline__ int basef(int g) {
    int yc = min(max(g, 0), HO - 1);
    return (int)floorf((float)yc * SC) - 2;
}

// Combined conv(gauss3, keys-cubic4) 6-tap. OOB coord -> all-zero weights (so
// the E1 dot2 chain yields exp2(-F5L2E) = exp(-5) = the zero-pad value).
__device__ __forceinline__ void tap6(int g, int* base_out, float w[6]) {
    int yc = min(max(g, 0), HO - 1);
    int base = basef(g);
#pragma unroll
    for (int s = 0; s < 6; ++s) w[s] = 0.0f;
    if (g >= 0 && g < HO) {
#pragma unroll
        for (int d = -1; d <= 1; ++d) {
            int yd = yc + d;
            if (yd < 0 || yd >= HO) continue;
            float src = (float)yd * SC;
            float fi0 = floorf(src);
            float tt = src - fi0;
            const float a = -0.75f;
            float t1 = tt + 1.0f;
            float c0 = ((a * t1 - 5.0f * a) * t1 + 8.0f * a) * t1 - 4.0f * a;
            float c1 = ((a + 2.0f) * tt - (a + 3.0f)) * tt * tt + 1.0f;
            float u = 1.0f - tt;
            float c2 = ((a + 2.0f) * u - (a + 3.0f)) * u * u + 1.0f;
            float u2 = 2.0f - tt;
            float c3 = ((a * u2 - 5.0f * a) * u2 + 8.0f * a) * u2 - 4.0f * a;
            int s0 = ((int)fi0 - 1) - base;   // in [0,2]
            float gg = (d == 0) ? GW1 : GW0;
            w[s0 + 0] += gg * c0;
            w[s0 + 1] += gg * c1;
            w[s0 + 2] += gg * c2;
            w[s0 + 3] += gg * c3;
        }
    }
    *base_out = base;
}

// pad 6 weights into 8-slot window at shift d (0/1) without dynamic indexing
__device__ __forceinline__ void pad8(const float w[6], int d, float scl, float w8[8]) {
#pragma unroll
    for (int j = 0; j < 8; ++j) {
        float a = (j < 6) ? w[j] : 0.0f;
        float bq = (j >= 1 && j < 7) ? w[j - 1] : 0.0f;
        w8[j] = ((d == 0) ? a : bq) * scl;
    }
}

__device__ __forceinline__ uint4 packw8(const float w8[8]) {
    uint4 r;
    r.x = __builtin_bit_cast(unsigned int, __floats2half2_rn(w8[0], w8[1]));
    r.y = __builtin_bit_cast(unsigned int, __floats2half2_rn(w8[2], w8[3]));
    r.z = __builtin_bit_cast(unsigned int, __floats2half2_rn(w8[4], w8[5]));
    r.w = __builtin_bit_cast(unsigned int, __floats2half2_rn(w8[6], w8[7]));
    return r;
}

// packed fp16 min — ROCm 7.2 headers lack __hmin2; emit v_pk_min_f16 directly
__device__ __forceinline__ __half2 hmin2(__half2 a, __half2 b) {
    unsigned int ua = __builtin_bit_cast(unsigned int, a);
    unsigned int ub = __builtin_bit_cast(unsigned int, b);
    unsigned int r;
    asm("v_pk_min_f16 %0, %1, %2" : "=v"(r) : "v"(ua), "v"(ub));
    return __builtin_bit_cast(__half2, r);
}

__global__ __launch_bounds__(256, 7) void k_fused(const float* __restrict__ in,
                                                  float* __restrict__ out) {
    __shared__ __align__(16) unsigned int Eu[68 * EW];   // E1 half, 10336 B (slice aliases)
    __shared__ __align__(16) unsigned int Hu[NRS * EW];  // hres half, 3648 B
    __shared__ uint4 xWu[72];                            // 1152 B (8 half weights, pairwise)
    __shared__ uint4 vWu[70];                            // 1120 B (x F5L2E)
    __shared__ int vgb[14], xgb[18];                     // 128 B  -> ~16.4 KB total
    float* SL = (float*)Eu;

    const int tid = threadIdx.x;
    const int bx = blockIdx.x, by = blockIdx.y, b = blockIdx.z;
    const int gy0 = by * TLE, gx0 = bx * TLE;
    const int rlo = basef(gy0 - 3);
    const int clo = basef(gx0 - 4);

    // ---- Phase 0a: issue slice global loads first (latency covered by 0b) ----
    const float* pin = in + b * (HI * WI);
    float g0, g1, g2 = 0.0f;
    {
        int i0 = tid, i1 = tid + 256;
        int r0 = i0 / NRS, c0 = i0 - r0 * NRS;
        int r1 = i1 / NRS, c1 = i1 - r1 * NRS;
        g0 = pin[min(max(rlo + r0, 0), HI - 1) * WI + min(max(clo + c0, 0), HI - 1)];
        g1 = pin[min(max(rlo + r1, 0), HI - 1) * WI + min(max(clo + c1, 0), HI - 1)];
        if (tid < 64) {
            int i2 = tid + 512;
            int r2 = i2 / NRS, c2 = i2 - r2 * NRS;
            g2 = pin[min(max(rlo + r2, 0), HI - 1) * WI + min(max(clo + c2, 0), HI - 1)];
        }
    }

    // ---- Phase 0b: packed fp16 weight tables ----
    if (tid < 70) {                       // vertical weights, fy = tid+1
        int fy = tid + 1;
        int base; float w[6];
        tap6(gy0 + fy - 3, &base, w);
        int q = tid / 5;
        int bs = basef(gy0 + (1 + 5 * q) - 3);
        float w8[8];
        pad8(w, base - bs, F5L2E, w8);
        vWu[tid] = packw8(w8);
    } else if (tid < 84) {
        vgb[tid - 70] = basef(gy0 + (1 + 5 * (tid - 70)) - 3);
    } else if (tid < 102) {
        xgb[tid - 84] = basef(gx0 + 4 * (tid - 84) - 4);
    } else if (tid >= 128 && tid < 200) { // horizontal weights, xe = tid-128
        int xe = tid - 128;
        int base; float w[6];
        tap6(gx0 + xe - 4, &base, w);
        int bs = basef(gx0 + (xe & ~3) - 4);
        float w8[8];
        pad8(w, base - bs, 1.0f, w8);
        xWu[xe] = packw8(w8);
    }

    // ---- Phase 0c: sigmoid + LDS write of the slice ----
    {
        int i0 = tid, i1 = tid + 256;
        int r0 = i0 / NRS, c0 = i0 - r0 * NRS;
        int r1 = i1 / NRS, c1 = i1 - r1 * NRS;
        SL[r0 * SSTR + c0] = 1.0f / (1.0f + __expf(-g0));
        SL[r1 * SSTR + c1] = 1.0f / (1.0f + __expf(-g1));
        if (tid < 64) {
            int i2 = tid + 512;
            int r2 = i2 / NRS, c2 = i2 - r2 * NRS;
            SL[r2 * SSTR + c2] = 1.0f / (1.0f + __expf(-g2));
        }
    }
    __syncthreads();

    const int ty = tid / 18;          // [0,14) for tid < 252
    const int tx = tid - ty * 18;

    // ---- Stage A: horizontal 6-tap via dot2 -> Hu (half) rows [0,24) ----
    if (tid < 252) {
        int cbg = xgb[tx] - clo;
        int wc[8];
#pragma unroll
        for (int j = 0; j < 8; ++j) wc[j] = min(cbg + j, NRS - 1);
        uint4 w0 = xWu[4 * tx + 0], w1 = xWu[4 * tx + 1];
        uint4 w2 = xWu[4 * tx + 2], w3 = xWu[4 * tx + 3];
        for (int r = ty; r < NRS; r += 14) {
            const float* srow = SL + r * SSTR;
            float v[8];
#pragma unroll
            for (int j = 0; j < 8; ++j) v[j] = srow[wc[j]];
            unsigned int p0 = __builtin_bit_cast(unsigned int, __floats2half2_rn(v[0], v[1]));
            unsigned int p1 = __builtin_bit_cast(unsigned int, __floats2half2_rn(v[2], v[3]));
            unsigned int p2 = __builtin_bit_cast(unsigned int, __floats2half2_rn(v[4], v[5]));
            unsigned int p3 = __builtin_bit_cast(unsigned int, __floats2half2_rn(v[6], v[7]));
            float s0 = dot2(w0.x, p0, dot2(w0.y, p1, dot2(w0.z, p2, dot2(w0.w, p3, 0.0f))));
            float s1 = dot2(w1.x, p0, dot2(w1.y, p1, dot2(w1.z, p2, dot2(w1.w, p3, 0.0f))));
            float s2 = dot2(w2.x, p0, dot2(w2.y, p1, dot2(w2.z, p2, dot2(w2.w, p3, 0.0f))));
            float s3 = dot2(w3.x, p0, dot2(w3.y, p1, dot2(w3.z, p2, dot2(w3.w, p3, 0.0f))));
            uint2 o;
            o.x = __builtin_bit_cast(unsigned int, __floats2half2_rn(s0, s1));
            o.y = __builtin_bit_cast(unsigned int, __floats2half2_rn(s2, s3));
            *reinterpret_cast<uint2*>(&Hu[r * EW + 2 * tx]) = o;
        }
    }
    __syncthreads();

    // ---- Stage B: vertical 6-tap via dot2 (row-pair repack) -> E1 rows fy 1..68 ----
    if (tid < 252) {
        const int q = ty;
        const int rbase = vgb[q] - rlo;
        unsigned int a01[8], a23[8];
#pragma unroll
        for (int i = 0; i < 8; ++i) {
            uint2 t = *reinterpret_cast<const uint2*>(&Hu[min(rbase + i, NRS - 1) * EW + 2 * tx]);
            a01[i] = t.x; a23[i] = t.y;
        }
        // repack to row pairs: pcK[p] = (h[2p][cK], h[2p+1][cK])
        unsigned int pc0[4], pc1[4], pc2[4], pc3[4];
#pragma unroll
        for (int p = 0; p < 4; ++p) {
            int j = 2 * p;
            pc0[p] = (a01[j] & 0xFFFFu) | (a01[j + 1] << 16);
            pc1[p] = (a01[j] >> 16) | (a01[j + 1] & 0xFFFF0000u);
            pc2[p] = (a23[j] & 0xFFFFu) | (a23[j + 1] << 16);
            pc3[p] = (a23[j] >> 16) | (a23[j + 1] & 0xFFFF0000u);
        }
#pragma unroll
        for (int i = 0; i < 5; ++i) {
            int fy = 1 + 5 * q + i;
            if (fy <= 68) {
                uint4 wv = vWu[fy - 1];
                float ax = dot2(wv.x, pc0[0], dot2(wv.y, pc0[1], dot2(wv.z, pc0[2], dot2(wv.w, pc0[3], -F5L2E))));
                float ay = dot2(wv.x, pc1[0], dot2(wv.y, pc1[1], dot2(wv.z, pc1[2], dot2(wv.w, pc1[3], -F5L2E))));
                float az = dot2(wv.x, pc2[0], dot2(wv.y, pc2[1], dot2(wv.z, pc2[2], dot2(wv.w, pc2[3], -F5L2E))));
                float aw = dot2(wv.x, pc3[0], dot2(wv.y, pc3[1], dot2(wv.z, pc3[2], dot2(wv.w, pc3[3], -F5L2E))));
                unsigned int p0 = __builtin_bit_cast(unsigned int, __floats2half2_rn(exp2f(ax), exp2f(ay)));
                unsigned int p1 = __builtin_bit_cast(unsigned int, __floats2half2_rn(exp2f(az), exp2f(aw)));
                *reinterpret_cast<uint2*>(&Eu[(fy - 1) * EW + 2 * tx]) = make_uint2(p0, p1);
            }
        }
    }
    __syncthreads();

    // ---- Stage CD: PACKED fp16 rolling E2 (pk_min) -> out (log), 4 rows/thread ----
    {
        const int dx = tid & 15;
        const int sq = tid >> 4;
        const int lr0 = 4 * sq;
        const bool rT = (by == 0)  && (sq == 0);
        const bool rB = (by == 15) && (sq == 15);
        const bool cL = (bx == 0)  && (dx == 0);
        const bool cR = (bx == 15) && (dx == 15);

        const __half2 ONE2 = __floats2half2_rn(1.0f, 1.0f);
        const __half2 EX2  = __floats2half2_rn(EXPM5, EXPM5);
        const unsigned int exu = __builtin_bit_cast(unsigned int, EX2);

        auto H2  = [](unsigned int u) { return __builtin_bit_cast(__half2, u); };
        auto U32 = [](__half2 h) { return __builtin_bit_cast(unsigned int, h); };

        // packed horizontal 3-sums of E1 row lr, halfs 4dx+2..4dx+9 -> P[0..2]=(hs0..hs5)
        auto HSUM = [&](int lr, __half2 P[3]) {
            const int o = lr * EW + 2 * dx;
            unsigned int a = Eu[o + 1];
            uint2 bc = *reinterpret_cast<const uint2*>(&Eu[o + 2]);
            unsigned int d = Eu[o + 4];
            unsigned int ab  = (a >> 16) | (bc.x << 16);      // (h1,h2)
            unsigned int bcx = (bc.x >> 16) | (bc.y << 16);   // (h3,h4)
            unsigned int cd  = (bc.y >> 16) | (d << 16);      // (h5,h6)
            P[0] = __hadd2(__hadd2(H2(a), H2(ab)), H2(bc.x));     // (hs0,hs1)
            P[1] = __hadd2(__hadd2(H2(bc.x), H2(bcx)), H2(bc.y)); // (hs2,hs3)
            P[2] = __hadd2(__hadd2(H2(bc.y), H2(cd)), H2(d));     // (hs4,hs5)
        };
        // E2 row = min(3-row sum, 1) + boundary overrides, then horiz 3-sum -> Q[0..1]
        auto E2F = [&](const __half2* a, const __half2* bq, const __half2* c,
                       bool rowOv, __half2 Q[2]) {
            __half2 e0 = hmin2(__hadd2(__hadd2(a[0], bq[0]), c[0]), ONE2);
            __half2 e1 = hmin2(__hadd2(__hadd2(a[1], bq[1]), c[1]), ONE2);
            __half2 e2 = hmin2(__hadd2(__hadd2(a[2], bq[2]), c[2]), ONE2);
            if (rowOv) { e0 = EX2; e1 = EX2; e2 = EX2; }
            if (cL) e0 = H2((U32(e0) & 0xFFFF0000u) | (exu & 0x0000FFFFu));
            if (cR) e2 = H2((U32(e2) & 0x0000FFFFu) | (exu & 0xFFFF0000u));
            unsigned int u0 = U32(e0), u1 = U32(e1), u2 = U32(e2);
            unsigned int e01 = (u0 >> 16) | (u1 << 16);
            unsigned int e12 = (u1 >> 16) | (u2 << 16);
            Q[0] = __hadd2(__hadd2(e0, H2(e01)), e1);   // (E0+E1+E2, E1+E2+E3)
            Q[1] = __hadd2(__hadd2(e1, H2(e12)), e2);   // (E2+E3+E4, E3+E4+E5)
        };
        auto OUTF = [&](const __half2* qa, const __half2* qb, const __half2* qc) -> float4 {
            __half2 s0 = __hadd2(__hadd2(qa[0], qb[0]), qc[0]);
            __half2 s1 = __hadd2(__hadd2(qa[1], qb[1]), qc[1]);
            float f0 = __low2float(s0), f1 = __high2float(s0);
            float f2 = __low2float(s1), f3 = __high2float(s1);
            float4 o;
            o.x = fmaxf(fminf(fmaf(C02, __log2f(f0), 1.0f), 1.0f), 0.0f);
            o.y = fmaxf(fminf(fmaf(C02, __log2f(f1), 1.0f), 1.0f), 0.0f);
            o.z = fmaxf(fminf(fmaf(C02, __log2f(f2), 1.0f), 1.0f), 0.0f);
            o.w = fmaxf(fminf(fmaf(C02, __log2f(f3), 1.0f), 1.0f), 0.0f);
            return o;
        };

        __half2 hA[3], hB[3], hC[3], hD[3];
        __half2 eA[2], eB[2], eC[2], eD[2], eE[2], eF[2];
        size_t obase = ((size_t)(b * HO + by * TLE + 4 * sq) * WO) + bx * TLE + (dx << 2);

        HSUM(lr0 + 0, hA); HSUM(lr0 + 1, hB); HSUM(lr0 + 2, hC);
        E2F(hA, hB, hC, rT, eA);
        HSUM(lr0 + 3, hD); E2F(hB, hC, hD, false, eB);
        HSUM(lr0 + 4, hA); E2F(hC, hD, hA, false, eC);
        *reinterpret_cast<float4*>(out + obase) = OUTF(eA, eB, eC); obase += WO;
        HSUM(lr0 + 5, hB); E2F(hD, hA, hB, false, eD);
        *reinterpret_cast<float4*>(out + obase) = OUTF(eB, eC, eD); obase += WO;
        HSUM(lr0 + 6, hC); E2F(hA, hB, hC, false, eE);
        *reinterpret_cast<float4*>(out + obase) = OUTF(eC, eD, eE); obase += WO;
        HSUM(lr0 + 7, hD); E2F(hB, hC, hD, rB, eF);
        *reinterpret_cast<float4*>(out + obase) = OUTF(eD, eE, eF);
    }
}

extern "C" void kernel_launch(void* const* d_in, const int* in_sizes, int n_in,
                              void* d_out, int out_size, void* d_ws, size_t ws_size,
                              hipStream_t stream) {
    const float* in = (const float*)d_in[0];
    float* out = (float*)d_out;
    dim3 g(WO / TLE, HO / TLE, B_);   // (16,16,8)
    k_fused<<<g, dim3(256), 0, stream>>>(in, out);
}